// Round 11
// baseline (2465.943 us; speedup 1.0000x reference)
//
#include <hip/hip_runtime.h>

#define RNN_T 2048
#define RNN_B 64
#define RNN_H 256

typedef _Float16 f16;
typedef _Float16 f16x4 __attribute__((ext_vector_type(4)));
typedef _Float16 f16x8 __attribute__((ext_vector_type(8)));
typedef float f32x4 __attribute__((ext_vector_type(4)));

// ---------------------------------------------------------------------------
// Kernel 1: xproj[b,t,:] = embed[x[b,t]] @ Wx + b_fc   (written into hs region)
// ---------------------------------------------------------------------------
__global__ __launch_bounds__(256)
void xproj_kernel(const int* __restrict__ x, const float* __restrict__ embed,
                  const float* __restrict__ Wfc, const float* __restrict__ bfc,
                  float* __restrict__ hsb) {
    __shared__ int ixs[64];
    __shared__ __align__(16) float A[64][260];
    const int tid = threadIdx.x;
    const long rb0 = (long)blockIdx.x * 64;

    if (tid < 64) ixs[tid] = x[rb0 + tid];
    __syncthreads();

    {
        const int r = tid >> 2, q = tid & 3;
        const float* erow = embed + (long)ixs[r] * RNN_H;
        #pragma unroll
        for (int i = 0; i < 16; ++i) {
            const int c = q * 64 + i * 4;
            *(float4*)&A[r][c] = *(const float4*)(erow + c);
        }
    }
    __syncthreads();

    const int tj = tid & 31, tr = tid >> 5;
    const int r0 = tr * 8, j0 = tj * 4, j1 = 128 + tj * 4;

    float acc[8][8];
    #pragma unroll
    for (int i = 0; i < 8; ++i)
        #pragma unroll
        for (int c = 0; c < 8; ++c) acc[i][c] = 0.f;

    for (int k4 = 0; k4 < 64; ++k4) {
        float4 a[8];
        #pragma unroll
        for (int i = 0; i < 8; ++i) a[i] = *(const float4*)&A[r0 + i][k4 * 4];
        #pragma unroll
        for (int kk = 0; kk < 4; ++kk) {
            const int k = k4 * 4 + kk;
            const float4 wa = *(const float4*)(Wfc + (long)k * RNN_H + j0);
            const float4 wb = *(const float4*)(Wfc + (long)k * RNN_H + j1);
            #pragma unroll
            for (int i = 0; i < 8; ++i) {
                const float av = reinterpret_cast<const float*>(&a[i])[kk];
                acc[i][0] = fmaf(av, wa.x, acc[i][0]);
                acc[i][1] = fmaf(av, wa.y, acc[i][1]);
                acc[i][2] = fmaf(av, wa.z, acc[i][2]);
                acc[i][3] = fmaf(av, wa.w, acc[i][3]);
                acc[i][4] = fmaf(av, wb.x, acc[i][4]);
                acc[i][5] = fmaf(av, wb.y, acc[i][5]);
                acc[i][6] = fmaf(av, wb.z, acc[i][6]);
                acc[i][7] = fmaf(av, wb.w, acc[i][7]);
            }
        }
    }

    const float4 ba = *(const float4*)(bfc + j0);
    const float4 bb = *(const float4*)(bfc + j1);
    #pragma unroll
    for (int i = 0; i < 8; ++i) {
        const long row = rb0 + r0 + i;
        float4 o1 = make_float4(acc[i][0] + ba.x, acc[i][1] + ba.y,
                                acc[i][2] + ba.z, acc[i][3] + ba.w);
        float4 o2 = make_float4(acc[i][4] + bb.x, acc[i][5] + bb.y,
                                acc[i][6] + bb.z, acc[i][7] + bb.w);
        *(float4*)(hsb + row * RNN_H + j0) = o1;
        *(float4*)(hsb + row * RNN_H + j1) = o2;
    }
}

// LDS-only barrier (R10 keeper): __syncthreads drains vmcnt(0) too; our only
// cross-lane dep is LDS, so lgkmcnt(0)+s_barrier suffices and keeps the
// per-step global hs-store off the critical path.
#define LDS_BARRIER() asm volatile("s_waitcnt lgkmcnt(0)\n\ts_barrier" ::: "memory")

#define TANH1(d, s) { const float _e = __expf(2.f * (s));                     \
                      d = 1.f - 2.f * __builtin_amdgcn_rcpf(_e + 1.f); }

// ---------------------------------------------------------------------------
// Kernel 2: MFMA RNN scan. 4 WGs x 16 batch rows, 256 thr (4 waves, 1/SIMD).
// D = Wh^T (A, loop-invariant regs/AGPRs - MFMA reads AGPRs natively, ending
// the R1-R10 residency war) x H^T (B, from LDS). mfma_f32_16x16x32_f16.
//   lane l: m = l&15 (batch row = D col per m89-verified C/D), g = l>>4.
//   wave wv owns n in [64wv, 64wv+64) = 4 n-tiles (D rows n = nt*16+g*4+reg).
//   K-mapping lane->k: k = kt*32 + g*8 + i for BOTH af and bf -> MFMA's
//   internal k-order cancels (K-permutation invariance).
// H in LDS: [16 m][256 k] fp16, byte ^= (m&15)<<4 swizzle -> b128 reads at
// the even-spread floor; writes: lane's 4 accs are k-consecutive -> 2x
// cvt-pairs -> ONE ds_write_b64 per n-tile (4 per wave per step).
// Per-step/CU: 32 b128 + 16 b64 DS ~510cy, MFMA 155cy/SIMD, tanh 16/lane.
// fp16 h/Wh, f32 accum + f32 tanh -> hs global (est err ~1e-3 < 2.5e-3).
// ---------------------------------------------------------------------------
__global__ __launch_bounds__(256, 1)
void rnn_scan_mfma(const float* __restrict__ Wfc, float* __restrict__ hsb) {
    __shared__ __align__(16) f16 hA[16 * RNN_H];
    __shared__ __align__(16) f16 hB[16 * RNN_H];
    const int tid = threadIdx.x;
    const int wg  = blockIdx.x;          // batch rows wg*16 .. +15
    const int wv = tid >> 6, l = tid & 63;
    const int m = l & 15, g = l >> 4;
    const int swz = m * 16;              // XOR swizzle (bits 4-7)

    // ---- A-fragments: af[nt][kt][i] = Wh^T[n][k] = Wh[k][n]
    const float* Wh = Wfc + RNN_H * RNN_H;
    f16x8 af[4][8];
    #pragma unroll
    for (int nt = 0; nt < 4; ++nt) {
        const int n = 64 * wv + nt * 16 + m;
        #pragma unroll
        for (int kt = 0; kt < 8; ++kt) {
            #pragma unroll
            for (int i = 0; i < 8; ++i) {
                const int k = kt * 32 + g * 8 + i;
                af[nt][kt][i] = (f16)Wh[k * RNN_H + n];
            }
        }
    }

    {   // zero h(0)
        int* z = (int*)hA;
        #pragma unroll
        for (int i = 0; i < 8; ++i) z[tid + 256 * i] = 0;
    }

    // xp / hs cursors: lane owns rows b = wg*16+m, cols n00+nt*16+{0..3}
    float* const xbase = hsb + (long)(wg * 16 + m) * RNN_T * RNN_H;
    const int n00 = 64 * wv + g * 4;

    f32x4 xr0 = *(const f32x4*)(xbase + n00 +  0);
    f32x4 xr1 = *(const f32x4*)(xbase + n00 + 16);
    f32x4 xr2 = *(const f32x4*)(xbase + n00 + 32);
    f32x4 xr3 = *(const f32x4*)(xbase + n00 + 48);
    f32x4 xn0 = *(const f32x4*)(xbase + RNN_H + n00 +  0);
    f32x4 xn1 = *(const f32x4*)(xbase + RNN_H + n00 + 16);
    f32x4 xn2 = *(const f32x4*)(xbase + RNN_H + n00 + 32);
    f32x4 xn3 = *(const f32x4*)(xbase + RNN_H + n00 + 48);

    const float* xpf  = xbase + 2 * RNN_H;            // prefetch cursor (t+2)
    const float* xend = xbase + (long)RNN_T * RNN_H;
    float*       xw   = xbase;                        // hs write cursor (t)

    char* const hAc = (char*)hA;
    char* const hBc = (char*)hB;

    __syncthreads();

#define RNN_STEP(RC, WC)                                                      \
    {                                                                         \
        f32x4 ac0 = {0,0,0,0}, ac1 = {0,0,0,0};                               \
        f32x4 ac2 = {0,0,0,0}, ac3 = {0,0,0,0};                               \
        _Pragma("unroll")                                                     \
        for (int kt = 0; kt < 8; ++kt) {                                      \
            const f16x8 bf = *(const f16x8*)(RC + m * 512 +                   \
                                             ((kt * 64 + g * 16) ^ swz));     \
            ac0 = __builtin_amdgcn_mfma_f32_16x16x32_f16(af[0][kt], bf, ac0, 0, 0, 0); \
            ac1 = __builtin_amdgcn_mfma_f32_16x16x32_f16(af[1][kt], bf, ac1, 0, 0, 0); \
            ac2 = __builtin_amdgcn_mfma_f32_16x16x32_f16(af[2][kt], bf, ac2, 0, 0, 0); \
            ac3 = __builtin_amdgcn_mfma_f32_16x16x32_f16(af[3][kt], bf, ac3, 0, 0, 0); \
        }                                                                     \
        const f32x4 s0 = ac0 + xr0, s1 = ac1 + xr1;                           \
        const f32x4 s2 = ac2 + xr2, s3 = ac3 + xr3;                           \
        f32x4 h0, h1, h2, h3;                                                 \
        TANH1(h0.x, s0.x) TANH1(h0.y, s0.y) TANH1(h0.z, s0.z) TANH1(h0.w, s0.w) \
        TANH1(h1.x, s1.x) TANH1(h1.y, s1.y) TANH1(h1.z, s1.z) TANH1(h1.w, s1.w) \
        TANH1(h2.x, s2.x) TANH1(h2.y, s2.y) TANH1(h2.z, s2.z) TANH1(h2.w, s2.w) \
        TANH1(h3.x, s3.x) TANH1(h3.y, s3.y) TANH1(h3.z, s3.z) TANH1(h3.w, s3.w) \
        f16x4 p0, p1, p2, p3;                                                 \
        p0.x=(f16)h0.x; p0.y=(f16)h0.y; p0.z=(f16)h0.z; p0.w=(f16)h0.w;       \
        p1.x=(f16)h1.x; p1.y=(f16)h1.y; p1.z=(f16)h1.z; p1.w=(f16)h1.w;       \
        p2.x=(f16)h2.x; p2.y=(f16)h2.y; p2.z=(f16)h2.z; p2.w=(f16)h2.w;       \
        p3.x=(f16)h3.x; p3.y=(f16)h3.y; p3.z=(f16)h3.z; p3.w=(f16)h3.w;       \
        *(f16x4*)(WC + m * 512 + (((n00 +  0) * 2) ^ swz)) = p0;              \
        *(f16x4*)(WC + m * 512 + (((n00 + 16) * 2) ^ swz)) = p1;              \
        *(f16x4*)(WC + m * 512 + (((n00 + 32) * 2) ^ swz)) = p2;              \
        *(f16x4*)(WC + m * 512 + (((n00 + 48) * 2) ^ swz)) = p3;              \
        *(f32x4*)(xw + n00 +  0) = h0;                                        \
        *(f32x4*)(xw + n00 + 16) = h1;                                        \
        *(f32x4*)(xw + n00 + 32) = h2;                                        \
        *(f32x4*)(xw + n00 + 48) = h3;                                        \
        xw += RNN_H;                                                          \
        xr0 = xn0; xr1 = xn1; xr2 = xn2; xr3 = xn3;                           \
        if (xpf < xend) {                                                     \
            xn0 = *(const f32x4*)(xpf + n00 +  0);                            \
            xn1 = *(const f32x4*)(xpf + n00 + 16);                            \
            xn2 = *(const f32x4*)(xpf + n00 + 32);                            \
            xn3 = *(const f32x4*)(xpf + n00 + 48);                            \
        }                                                                     \
        xpf += RNN_H;                                                         \
        LDS_BARRIER();                                                        \
    }

    for (int t = 0; t < RNN_T; t += 2) {
        RNN_STEP(hAc, hBc);   // even: read hA, write hB
        RNN_STEP(hBc, hAc);   // odd:  read hB, write hA
    }
#undef RNN_STEP
}

// ---------------------------------------------------------------------------
// Kernel 3: out[b,:] = hs[b, T-1, :] @ W_out + b_out  (f32, from global hs)
// ---------------------------------------------------------------------------
__global__ __launch_bounds__(256)
void out_kernel(const float* __restrict__ hsb, const float* __restrict__ Wout,
                const float* __restrict__ bout, float* __restrict__ out) {
    const int b = blockIdx.x, n = threadIdx.x;
    const float* hl = hsb + ((long)b * RNN_T + (RNN_T - 1)) * RNN_H;
    float a0 = 0.f, a1 = 0.f, a2 = 0.f, a3 = 0.f;
    for (int k = 0; k < RNN_H; k += 4) {
        a0 = fmaf(hl[k + 0], Wout[(long)(k + 0) * RNN_H + n], a0);
        a1 = fmaf(hl[k + 1], Wout[(long)(k + 1) * RNN_H + n], a1);
        a2 = fmaf(hl[k + 2], Wout[(long)(k + 2) * RNN_H + n], a2);
        a3 = fmaf(hl[k + 3], Wout[(long)(k + 3) * RNN_H + n], a3);
    }
    out[(long)b * RNN_H + n] = a0 + a1 + a2 + a3 + bout[n];
}

extern "C" void kernel_launch(void* const* d_in, const int* in_sizes, int n_in,
                              void* d_out, int out_size, void* d_ws, size_t ws_size,
                              hipStream_t stream) {
    const int*   x     = (const int*)d_in[0];
    const float* embed = (const float*)d_in[1];
    const float* Wfc   = (const float*)d_in[2];
    const float* bfc   = (const float*)d_in[3];
    const float* Wout  = (const float*)d_in[4];
    const float* bout  = (const float*)d_in[5];

    float* out = (float*)d_out;                 // [B, 256]
    float* hsb = out + RNN_B * RNN_H;           // [B, T, H] region

    xproj_kernel<<<(RNN_B * RNN_T) / 64, 256, 0, stream>>>(x, embed, Wfc, bfc, hsb);
    rnn_scan_mfma<<<4, 256, 0, stream>>>(Wfc, hsb);
    out_kernel<<<RNN_B, 256, 0, stream>>>(hsb, Wout, bout, out);
}